// Round 4
// baseline (85.152 us; speedup 1.0000x reference)
//
#include <hip/hip_runtime.h>
#include <hip/hip_bf16.h>

// MeanPooling: out[b,e,d] = (sum_l map[b,e,l]*doc[b,l,d]) / lens[b,e]
// B=16, E=256, L=4096 (=K), D=512. fp32 in/out, bf16 MFMA inside.
//
// R4: manual async pipeline (R2/R3 failed because compiler collapsed the
// prefetch). 512 blocks x 4 waves, split-K x4, 64x64 tile/wave, NO barriers
// in k-loop (wave-private LDS ring-2 for B).
//  - B: global_load_lds width-16 (async, no VGPR round trip, unsinkable),
//    source-side chunk swizzle (slot c' = cg + 2*(k>>3) mod 16) so the
//    strided ds_read_b32 frag reads are 2-way (free).
//  - A: inline-asm global_load_dwordx4, ping-pong regs (position pinned).
//  - Hand-counted s_waitcnt vmcnt(16) per sub-iter (16 = one prefetched
//    tile's 8 B + 8 A loads), lgkmcnt(0) + sched_barrier(0) per rule 18.

#define NB 16
#define NE 256
#define NL 4096
#define ND 512
#define KSPLIT 4
#define KPW (NL / KSPLIT)   // 1024 per wave
#define NT (KPW / 32)       // 32 k-tiles of 32 per wave

using f32x4  = __attribute__((ext_vector_type(4))) float;
using bf16x8 = __attribute__((ext_vector_type(8))) short;

static __device__ __forceinline__ short f2bf(float x) {
  __bf16 h = (__bf16)x;   // hardware RNE convert
  return __builtin_bit_cast(short, h);
}

static __device__ __forceinline__ unsigned lds_u32(const void* p) {
  return (unsigned)(size_t)(const __attribute__((address_space(3))) void*)p;
}

// async global->LDS, 16B/lane; LP wave-uniform base, GP per-lane source
#define GLDS16(GP, LP)                                                         \
  __builtin_amdgcn_global_load_lds(                                            \
      (const __attribute__((address_space(1))) void*)(GP),                     \
      (__attribute__((address_space(3))) void*)(LP), 16, 0, 0)

#define GLOADX4(DST, PTR)                                                      \
  asm volatile("global_load_dwordx4 %0, %1, off" : "=v"(DST) : "v"(PTR))

#define DSR(DST, ADDR, OFF)                                                    \
  asm volatile("ds_read_b32 %0, %1 offset:" OFF : "=v"(DST) : "v"(ADDR))

#define WAIT_VM16() asm volatile("s_waitcnt vmcnt(16)")
#define WAIT_VM0()  asm volatile("s_waitcnt vmcnt(0)")
#define WAIT_LGKM() asm volatile("s_waitcnt lgkmcnt(0)")
#define SB0()       __builtin_amdgcn_sched_barrier(0)

// Ar regs (fp32) -> 4 bf16x8 A fragments
#define CVTA(FR, AR)                                                           \
  _Pragma("unroll") for (int m_ = 0; m_ < 4; ++m_)                             \
      _Pragma("unroll") for (int j_ = 0; j_ < 4; ++j_) {                       \
    FR[m_][j_]     = f2bf(AR[2 * m_][j_]);                                     \
    FR[m_][4 + j_] = f2bf(AR[2 * m_ + 1][j_]);                                 \
  }

// issue one B tile (8 x gload_lds) + one A tile (8 x asm dwordx4)
#define PREFETCH(BUF, AR, PT)                                                  \
  do {                                                                         \
    const char* gb_ = bgBase + (size_t)(PT) * 65536;                           \
    _Pragma("unroll") for (int j_ = 0; j_ < 8; ++j_)                           \
        GLDS16(gb_ + bw[j_], bufB + (size_t)(BUF) * 8192 + j_ * 1024);         \
    _Pragma("unroll") for (int m_ = 0; m_ < 4; ++m_) {                         \
      GLOADX4(AR[2 * m_],     aPtr[m_] + (size_t)(PT) * 32);                   \
      GLOADX4(AR[2 * m_ + 1], aPtr[m_] + (size_t)(PT) * 32 + 4);               \
    }                                                                          \
  } while (0)

// consume tile in buffer BUF + A regs AR, then prefetch tile PT into them
#define SUBITER(BUF, AR, PT)                                                   \
  do {                                                                         \
    WAIT_VM16();                                                               \
    SB0();                                                                     \
    bf16x8 af_[4];                                                             \
    CVTA(af_, AR);                                                             \
    float tb_[4][8];                                                           \
    _Pragma("unroll") for (int n_ = 0; n_ < 4; ++n_) {                         \
      unsigned ra_ = rdA[n_] + (BUF) * 8192;                                   \
      DSR(tb_[n_][0], ra_, "0");    DSR(tb_[n_][1], ra_, "256");               \
      DSR(tb_[n_][2], ra_, "512");  DSR(tb_[n_][3], ra_, "768");               \
      DSR(tb_[n_][4], ra_, "1024"); DSR(tb_[n_][5], ra_, "1280");              \
      DSR(tb_[n_][6], ra_, "1536"); DSR(tb_[n_][7], ra_, "1792");              \
    }                                                                          \
    WAIT_LGKM();                                                               \
    SB0();                                                                     \
    bf16x8 bf_[4];                                                             \
    _Pragma("unroll") for (int n_ = 0; n_ < 4; ++n_)                           \
        _Pragma("unroll") for (int j_ = 0; j_ < 8; ++j_)                       \
            bf_[n_][j_] = f2bf(tb_[n_][j_]);                                   \
    __builtin_amdgcn_s_setprio(1);                                             \
    _Pragma("unroll") for (int m_ = 0; m_ < 4; ++m_)                           \
        _Pragma("unroll") for (int n_ = 0; n_ < 4; ++n_)                       \
            acc[m_][n_] = __builtin_amdgcn_mfma_f32_16x16x32_bf16(             \
                af_[m_], bf_[n_], acc[m_][n_], 0, 0, 0);                       \
    __builtin_amdgcn_s_setprio(0);                                             \
    SB0();                                                                     \
    PREFETCH(BUF, AR, PT);                                                     \
    SB0();                                                                     \
  } while (0)

__global__ __launch_bounds__(256, 2) void mp_gemm(const float* __restrict__ doc,
                                                  const float* __restrict__ emap,
                                                  const float* __restrict__ lens,
                                                  float* __restrict__ out) {
  // 64KB: per-wave [2 bufs][8KB] B ring; aliased per-wave 16KB partial buffer.
  __shared__ float smem[4 * 4096];

  int bid = (int)blockIdx.x;
  // XCD-chunk swizzle: XCD x gets logical blocks [64x, 64x+63]
  int logical = (bid & 7) * 64 + (bid >> 3);
  int b  = logical >> 5;        // 16 batches (2 per XCD chunk)
  int et = (logical >> 3) & 3;  // 4 e-tiles of 64 rows
  int dt = logical & 7;         // 8 d-tiles of 64 cols

  int tid  = (int)threadIdx.x;
  int w    = tid >> 6;          // wave = K-split index
  int lane = tid & 63;
  int l15  = lane & 15;
  int g    = lane >> 4;         // frag k-group 0..3
  int q    = lane >> 4;         // staging row-in-group
  int r    = lane & 15;         // staging chunk

  char* bufB = (char*)(smem + w * 4096);   // this wave's 16KB region

  // --- B staging: LDS [32k][16 chunks]; slot(k,c') holds global chunk
  //     (c' - 2*(k>>3)) & 15.  Write instr j covers rows 4j+q, chunk r. ---
  int bw[8];
#pragma unroll
  for (int j = 0; j < 8; ++j)
    bw[j] = (4 * j + q) * 2048 + (((r - 2 * (j >> 1)) & 15) << 4);

  // read: frag n, lane (l15,g) wants (k=8g+j, dword 16n+l15):
  //   slot chunk c' = (4n + (l15>>2) + 2g) & 15  (j-independent since k>>3=g)
  unsigned rdA[4];
#pragma unroll
  for (int n = 0; n < 4; ++n)
    rdA[n] = lds_u32(bufB) + (unsigned)(g * 2048 +
             (((4 * n + (l15 >> 2) + 2 * g) & 15) << 4) + (l15 & 3) * 4);

  const char* bgBase = (const char*)doc +
      ((size_t)b * NL * ND + (size_t)w * KPW * ND) * 4 + (size_t)dt * 256;

  const float* Ab = emap + (size_t)(b * NE + et * 64) * NL;  // [64][L]
  const float* aPtr[4];
#pragma unroll
  for (int m = 0; m < 4; ++m)
    aPtr[m] = Ab + (size_t)(16 * m + l15) * NL + w * KPW + 8 * g;

  f32x4 acc[4][4] = {};  // rows 4g..4g+3, col l15 per frag
  f32x4 Ar0[8], Ar1[8];

  // prologue: issue order defines vmcnt windows: B0(8) A0(8) B1(8) A1(8)
  PREFETCH(0, Ar0, 0);
  SB0();
  PREFETCH(1, Ar1, 1);
  SB0();

#pragma unroll 1
  for (int t = 0; t < NT; t += 2) {
    int p2 = t + 2 < NT ? t + 2 : NT - 1;  // clamped (buffer already consumed)
    int p3 = t + 3 < NT ? t + 3 : NT - 1;
    SUBITER(0, Ar0, p2);
    SUBITER(1, Ar1, p3);
  }

  WAIT_VM0();   // drain the dangling clamped prefetches before aliasing LDS
  SB0();

  // fp32 partials -> own 16KB region. C/D frag: row=16m+4g+i, col=16n+l15.
  float* myT = smem + w * 4096;
#pragma unroll
  for (int m = 0; m < 4; ++m)
#pragma unroll
    for (int n = 0; n < 4; ++n)
#pragma unroll
      for (int i = 0; i < 4; ++i)
        myT[(16 * m + 4 * g + i) * 64 + 16 * n + l15] = acc[m][n][i];

  __syncthreads();

  // Cross-wave reduce + divide + store: 256 threads x 16 passes over 64x64.
  const float* lb = lens + b * NE + et * 64;
  float* ob = out + (size_t)(b * NE + et * 64) * ND + dt * 64;
#pragma unroll
  for (int p = 0; p < 16; ++p) {
    int idx = p * 256 + tid;
    float s = smem[idx] + smem[4096 + idx] + smem[8192 + idx] + smem[12288 + idx];
    int row = idx >> 6;
    int col = idx & 63;
    ob[(size_t)row * ND + col] = s / lb[row];
  }
}

extern "C" void kernel_launch(void* const* d_in, const int* in_sizes, int n_in,
                              void* d_out, int out_size, void* d_ws, size_t ws_size,
                              hipStream_t stream) {
  const float* doc  = (const float*)d_in[0];  // (B, L, D)
  const float* emap = (const float*)d_in[1];  // (B, E, L)
  const float* lens = (const float*)d_in[2];  // (B, E)
  float* out = (float*)d_out;                 // (B, E, D)
  hipLaunchKernelGGL(mp_gemm, dim3(512), dim3(256), 0, stream, doc, emap, lens, out);
}

// Round 7
// 80.885 us; speedup vs baseline: 1.0528x; 1.0528x over previous
//
#include <hip/hip_runtime.h>
#include <hip/hip_bf16.h>

// MeanPooling: out[b,e,d] = (sum_l map[b,e,l]*doc[b,l,d]) / lens[b,e]
// B=16, E=256, L=4096 (=K), D=512. fp32 in/out, bf16 MFMA inside.
//
// R7: drop ds_read_b64_tr_b16 (two failed rounds on its semantics).
// B transpose now happens at ds_write time: B' stored [d][k] bf16 in LDS,
// so B-frag reads are plain ds_read_b128 (same shape as A reads,
// conflict-free). B global staging = per-thread k-column (16 coalesced
// dword loads, thread owns d=t>>1, k-half=t&1), LDS-contiguous ->
// 2 x ds_write_b128 with chunk swizzle c^=(d>>2)&3 (write AND read both
// at the 8-lanes/bank-quad minimum, hand-counted).
//
// Structure (R5): 128x128 block tile (32 FLOP/B), split-K x4, 512 blocks
// (2/CU), 4 waves = 2x2 quadrants of 64x64. Depth-2 prefetch, raw s_barrier,
// counted vmcnt(20) (20 loads/tile: 4 A dwordx4 + 16 B dword), no vmcnt(0)
// in-loop. Split-K reduced via memsetAsync + unsafeAtomicAdd; swizzle keeps
// each XCD on 2 whole batches and ks-siblings adjacent (atomics L2-local).

#define NB 16
#define NE 256
#define NL 4096
#define ND 512
#define KSPLIT 4
#define KPW (NL / KSPLIT)   // 1024 per block
#define BK 32
#define NT (KPW / BK)       // 32 k-steps

using f32x4  = __attribute__((ext_vector_type(4))) float;
using u32x2  = __attribute__((ext_vector_type(2))) unsigned;
using u32x4  = __attribute__((ext_vector_type(4))) unsigned;
using bf16x8 = __attribute__((ext_vector_type(8))) short;

static __device__ __forceinline__ unsigned bfbits(float x) {
  return (unsigned)__builtin_bit_cast(unsigned short, (__bf16)x);  // RNE
}
static __device__ __forceinline__ u32x2 pack4(f32x4 v) {
  u32x2 r;
  r[0] = bfbits(v[0]) | (bfbits(v[1]) << 16);
  r[1] = bfbits(v[2]) | (bfbits(v[3]) << 16);
  return r;
}
static __device__ __forceinline__ unsigned lds_u32(const void* p) {
  return (unsigned)(size_t)(const __attribute__((address_space(3))) void*)p;
}

#define GLOADX4(DST, PTR) \
  asm volatile("global_load_dwordx4 %0, %1, off" : "=v"(DST) : "v"(PTR))
#define GLOADX1(DST, PTR) \
  asm volatile("global_load_dword %0, %1, off" : "=v"(DST) : "v"(PTR))
#define DSWRITE64(ADDR, DATA) \
  asm volatile("ds_write_b64 %0, %1" :: "v"(ADDR), "v"(DATA) : "memory")
#define DSWRITE128(ADDR, DATA) \
  asm volatile("ds_write_b128 %0, %1" :: "v"(ADDR), "v"(DATA) : "memory")
#define DSREAD128(DST, ADDR) \
  asm volatile("ds_read_b128 %0, %1" : "=v"(DST) : "v"(ADDR))
#define WAIT_VM(N)  asm volatile("s_waitcnt vmcnt(" #N ")" ::: "memory")
#define WAIT_LGKM() asm volatile("s_waitcnt lgkmcnt(0)" ::: "memory")
#define SB0()       __builtin_amdgcn_sched_barrier(0)

// issue one k-step's staging loads: A 4 x dwordx4, B 16 x dword per thread
#define STAGE_ISSUE(RA, RB, T)                                                 \
  do {                                                                         \
    const float* pa_ = gAthr + (size_t)(T) * BK;                               \
    const float* pb_ = gBthr + (size_t)(T) * BK * ND;                          \
    GLOADX4(RA[0], pa_);                GLOADX4(RA[1], pa_ + 32 * NL);         \
    GLOADX4(RA[2], pa_ + 64 * NL);      GLOADX4(RA[3], pa_ + 96 * NL);         \
    _Pragma("unroll") for (int i_ = 0; i_ < 16; ++i_)                          \
        GLOADX1(RB[i_], pb_ + (size_t)i_ * ND);                                \
  } while (0)

// convert staged regs to bf16 and write into LDS buffer at BUFOFF
#define STAGE_WRITE(RA, RB, BUFOFF)                                            \
  do {                                                                         \
    _Pragma("unroll") for (int i_ = 0; i_ < 4; ++i_) {                         \
      u32x2 d_ = pack4(RA[i_]);                                                \
      DSWRITE64(awAddr[i_] + (BUFOFF), d_);                                    \
    }                                                                          \
    _Pragma("unroll") for (int i_ = 0; i_ < 2; ++i_) {                         \
      u32x4 w_;                                                                \
      _Pragma("unroll") for (int j_ = 0; j_ < 4; ++j_)                         \
          w_[j_] = bfbits(RB[8 * i_ + 2 * j_]) |                               \
                   (bfbits(RB[8 * i_ + 2 * j_ + 1]) << 16);                    \
      DSWRITE128(bwAddr[i_] + (BUFOFF), w_);                                   \
    }                                                                          \
  } while (0)

// frag reads (plain b128 for both A and B) + 16 MFMA from buffer at BUFOFF
#define COMPUTE(BUFOFF)                                                        \
  do {                                                                         \
    bf16x8 af_[4], bf_[4];                                                     \
    DSREAD128(af_[0], aRd[0] + (BUFOFF));                                      \
    DSREAD128(af_[1], aRd[1] + (BUFOFF));                                      \
    DSREAD128(af_[2], aRd[2] + (BUFOFF));                                      \
    DSREAD128(af_[3], aRd[3] + (BUFOFF));                                      \
    DSREAD128(bf_[0], bRd[0] + (BUFOFF));                                      \
    DSREAD128(bf_[1], bRd[1] + (BUFOFF));                                      \
    DSREAD128(bf_[2], bRd[2] + (BUFOFF));                                      \
    DSREAD128(bf_[3], bRd[3] + (BUFOFF));                                      \
    WAIT_LGKM();                                                               \
    SB0();                                                                     \
    __builtin_amdgcn_s_setprio(1);                                             \
    _Pragma("unroll") for (int m_ = 0; m_ < 4; ++m_)                           \
        _Pragma("unroll") for (int n_ = 0; n_ < 4; ++n_)                       \
            acc[m_][n_] = __builtin_amdgcn_mfma_f32_16x16x32_bf16(             \
                af_[m_], bf_[n_], acc[m_][n_], 0, 0, 0);                       \
    __builtin_amdgcn_s_setprio(0);                                             \
    SB0();                                                                     \
  } while (0)

__global__ __launch_bounds__(256, 2) void mp_gemm(const float* __restrict__ doc,
                                                  const float* __restrict__ emap,
                                                  const float* __restrict__ lens,
                                                  float* __restrict__ out) {
  // 2 bufs x (A' [128][32] bf16 8KB + B' [128 d][32 k] bf16 8KB) = 32KB
  __shared__ char smem[2 * 16384];

  int bid = (int)blockIdx.x;
  // XCD swizzle: XCD x owns logical [64x, 64x+63] = 2 whole batches.
  int logical = (bid & 7) * 64 + (bid >> 3);
  int b    = logical >> 5;
  int rest = logical & 31;
  int et = rest >> 4;         // e-tile of 128 (2)
  int dt = (rest >> 2) & 3;   // d-tile of 128 (4)
  int ks = rest & 3;          // k-split (4); siblings adjacent -> same XCD

  int tid  = (int)threadIdx.x;
  int w    = tid >> 6;
  int wr   = w >> 1;          // wave row 0..1 (64 rows)
  int wc   = w & 1;           // wave col 0..1 (64 cols)
  int lane = tid & 63;
  int l15  = lane & 15;
  int g    = lane >> 4;

  unsigned ldsb = lds_u32(smem);

  // ---- staging addresses ----
  // A: thread covers rows (tid>>3)+32i, 16B chunk (tid&7) of the 128B k-slice
  const float* gAthr = emap + (size_t)(b * NE + et * 128 + (tid >> 3)) * NL +
                       ks * KPW + (tid & 7) * 4;
  // B: thread owns d-column (tid>>1), k-half (tid&1): 16 k-rows of one dword
  const float* gBthr = doc +
      ((size_t)b * NL + ks * KPW + 16 * (tid & 1)) * ND + dt * 128 + (tid >> 1);

  // A' write: [row][32k] bf16, row*64 + chunk*8  (b64, 4 lanes/bank = min)
  unsigned awAddr[4];
#pragma unroll
  for (int i = 0; i < 4; ++i)
    awAddr[i] = ldsb + ((tid >> 3) + 32 * i) * 64 + (tid & 7) * 8;
  // B' write: [d][32k] bf16 at 8192; chunk c (16B = 8 k) swizzled c^=(d>>2)&3
  unsigned bwAddr[2];
  {
    int d = tid >> 1;
#pragma unroll
    for (int i = 0; i < 2; ++i) {
      int c = 2 * (tid & 1) + i;
      bwAddr[i] = ldsb + 8192 + d * 64 + ((c ^ ((d >> 2) & 3)) << 4);
    }
  }

  // ---- fragment read addresses (both plain b128) ----
  unsigned aRd[4], bRd[4];
#pragma unroll
  for (int m = 0; m < 4; ++m)
    aRd[m] = ldsb + (64 * wr + 16 * m + l15) * 64 + g * 16;
#pragma unroll
  for (int n = 0; n < 4; ++n) {
    int d = 64 * wc + 16 * n + l15;
    bRd[n] = ldsb + 8192 + d * 64 + ((g ^ ((d >> 2) & 3)) << 4);
  }

  f32x4 acc[4][4] = {};
  f32x4 RA0[4], RA1[4];
  float RB0[16], RB1[16];

  // prologue: L0 -> set0, L1 -> set1; write buf0 <- set0
  STAGE_ISSUE(RA0, RB0, 0);
  SB0();
  STAGE_ISSUE(RA1, RB1, 1);
  SB0();
  WAIT_VM(20);                 // tile0's 20 loads landed
  SB0();
  STAGE_WRITE(RA0, RB0, 0);

#pragma unroll 1
  for (int t = 0; t < NT; t += 2) {
    int p2 = t + 2 < NT ? t + 2 : NT - 1;  // clamped prefetch (tail-safe)
    int p3 = t + 3 < NT ? t + 3 : NT - 1;
    // even: compute buf0 (tile t); issue L(t+2)->set0; write buf1 <- set1
    WAIT_LGKM();
    __builtin_amdgcn_s_barrier();
    SB0();
    STAGE_ISSUE(RA0, RB0, p2);
    SB0();
    COMPUTE(0);
    WAIT_VM(20);               // tile t+1's loads landed (t+2's still out)
    SB0();
    STAGE_WRITE(RA1, RB1, 16384);
    // odd: compute buf1 (tile t+1); issue L(t+3)->set1; write buf0 <- set0
    WAIT_LGKM();
    __builtin_amdgcn_s_barrier();
    SB0();
    STAGE_ISSUE(RA1, RB1, p3);
    SB0();
    COMPUTE(16384);
    WAIT_VM(20);               // tile t+2's loads landed
    SB0();
    STAGE_WRITE(RA0, RB0, 0);
  }

  WAIT_VM(0);   // dangling clamped prefetches must land before regs reused
  SB0();

  // epilogue: divide by lens, atomic-accumulate the k-split partial.
  // C/D frag: row = 16m + 4g + i, col = 16n + l15 (within 64x64 quadrant).
  const float* lb = lens + b * NE + et * 128 + 64 * wr;
  float* ob = out + (size_t)(b * NE + et * 128 + 64 * wr) * ND + dt * 128 + 64 * wc;
#pragma unroll
  for (int m = 0; m < 4; ++m) {
#pragma unroll
    for (int i = 0; i < 4; ++i) {
      int row = 16 * m + 4 * g + i;
      float inv = 1.0f / lb[row];
#pragma unroll
      for (int n = 0; n < 4; ++n)
        unsafeAtomicAdd(&ob[(size_t)row * ND + 16 * n + l15], acc[m][n][i] * inv);
    }
  }
}

extern "C" void kernel_launch(void* const* d_in, const int* in_sizes, int n_in,
                              void* d_out, int out_size, void* d_ws, size_t ws_size,
                              hipStream_t stream) {
  const float* doc  = (const float*)d_in[0];  // (B, L, D)
  const float* emap = (const float*)d_in[1];  // (B, E, L)
  const float* lens = (const float*)d_in[2];  // (B, E)
  float* out = (float*)d_out;                 // (B, E, D)
  hipMemsetAsync(out, 0, (size_t)NB * NE * ND * sizeof(float), stream);
  hipLaunchKernelGGL(mp_gemm, dim3(512), dim3(256), 0, stream, doc, emap, lens, out);
}